// Round 1
// baseline (7561.420 us; speedup 1.0000x reference)
//
#include <hip/hip_runtime.h>
#include <math.h>

#define D      1024
#define NHEADS 16
#define HDIM   64
#define NL     2
#define FF     4096
#define NGRP   15
#define VOC    2048
#define TOPK   50
#define MAXS   16

__device__ __forceinline__ float wave_reduce_sum(float v) {
#pragma unroll
    for (int m = 32; m >= 1; m >>= 1) v += __shfl_xor(v, m, 64);
    return v;
}

// 256-thread block helper: xn[] = rms(src)*w, red[] is 256-float scratch.
__device__ __forceinline__ void load_rms(const float* __restrict__ src,
                                         const float* __restrict__ w,
                                         float* xn, float* red) {
    int tid = threadIdx.x;
    float ss = 0.f;
    for (int i = tid; i < D; i += 256) { float v = src[i]; xn[i] = v; ss += v * v; }
    red[tid] = ss;
    __syncthreads();
    for (int s = 128; s > 0; s >>= 1) {
        if (tid < s) red[tid] += red[tid + s];
        __syncthreads();
    }
    float inv = rsqrtf(red[0] / (float)D + 1e-6f);
    for (int i = tid; i < D; i += 256) xn[i] = xn[i] * inv * w[i];
    __syncthreads();
}

__global__ void k_init(const float* __restrict__ th, const float* __restrict__ c0,
                       float* __restrict__ h, float* __restrict__ out) {
    int i = blockIdx.x * 256 + threadIdx.x;   // grid 4 x 256 -> i < 1024
    h[i] = th[i];
    h[D + i] = c0[i];
    out[NGRP + i] = c0[i];
}

// q/k/v matvec with fused rms(ln1). grid (T, 3, 32), block 256.
// Each block: 32 outputs, 8 input-chunks of 128.
__global__ void k_qkv(const float* __restrict__ h, const float* __restrict__ ln,
                      const float* __restrict__ Wq, const float* __restrict__ Wk,
                      const float* __restrict__ Wv, float* __restrict__ qkv) {
    __shared__ float xn[D];
    __shared__ float red[256];
    int t = blockIdx.x, m = blockIdx.y, ob = blockIdx.z;
    load_rms(h + t * D, ln, xn, red);
    const float* W = (m == 0) ? Wq : (m == 1) ? Wk : Wv;
    int tid = threadIdx.x;
    int o = ob * 32 + (tid & 31);
    int c = tid >> 5;
    const float* Wp = W + o;
    float acc = 0.f;
    int i0 = c * 128;
    for (int i = i0; i < i0 + 128; ++i) acc += xn[i] * Wp[i * D];
    red[tid] = acc;
    __syncthreads();
    if (tid < 32) {
        float s = 0.f;
#pragma unroll
        for (int k = 0; k < 8; ++k) s += red[k * 32 + tid];
        qkv[t * 3 * D + m * D + ob * 32 + tid] = s;
    }
}

// attention with fused rope + cache write. grid (T, NHEADS), block 64 (one wave).
__global__ void k_attn(const float* __restrict__ qkv, float* __restrict__ kc,
                       float* __restrict__ vc, float* __restrict__ ao, int basePos) {
    int t = blockIdx.x, hd = blockIdx.y, d = threadIdx.x;
    int pos = basePos + t;
    int i = d & 31;
    float inv = __expf(-(float)i * (9.210340371976184f / 32.0f)); // 10000^(-i/32)
    float ang = (float)pos * inv;
    float cs = cosf(ang), sn = sinf(ang);

    float q = qkv[t * 3 * D + hd * HDIM + d];
    float qp = __shfl_xor(q, 32, 64);
    float qr = (d < 32) ? (q * cs - qp * sn) : (q * cs + qp * sn);

    float k0 = qkv[t * 3 * D + D + hd * HDIM + d];
    float kp = __shfl_xor(k0, 32, 64);
    float kr = (d < 32) ? (k0 * cs - kp * sn) : (k0 * cs + kp * sn);

    float v0 = qkv[t * 3 * D + 2 * D + hd * HDIM + d];
    kc[pos * D + hd * HDIM + d] = kr;
    vc[pos * D + hd * HDIM + d] = v0;

    float sc[MAXS];
#pragma unroll
    for (int s = 0; s < MAXS; ++s) {
        if (s > pos) break;
        float kv;
        if (s < basePos) {
            kv = kc[s * D + hd * HDIM + d];
        } else if (s == pos) {
            kv = kr;
        } else {
            float kk = qkv[(s - basePos) * 3 * D + D + hd * HDIM + d];
            float kkp = __shfl_xor(kk, 32, 64);
            float a2 = (float)s * inv;
            float c2 = cosf(a2), s2 = sinf(a2);
            kv = (d < 32) ? (kk * c2 - kkp * s2) : (kk * c2 + kkp * s2);
        }
        float dt = wave_reduce_sum(qr * kv);
        sc[s] = dt * 0.125f;  // 1/sqrt(64)
    }
    float mx = -1e30f;
#pragma unroll
    for (int s = 0; s < MAXS; ++s) { if (s > pos) break; mx = fmaxf(mx, sc[s]); }
    float l = 0.f;
#pragma unroll
    for (int s = 0; s < MAXS; ++s) { if (s > pos) break; sc[s] = expf(sc[s] - mx); l += sc[s]; }
    float o = 0.f;
#pragma unroll
    for (int s = 0; s < MAXS; ++s) {
        if (s > pos) break;
        float vv = (s < basePos) ? vc[s * D + hd * HDIM + d]
                                 : qkv[(s - basePos) * 3 * D + 2 * D + hd * HDIM + d];
        o += sc[s] * vv;
    }
    ao[t * D + hd * HDIM + d] = o / l;
}

// h += attn_out @ Wo. grid (T, 32), block 256.
__global__ void k_wo(const float* __restrict__ ain, const float* __restrict__ W,
                     float* __restrict__ h) {
    __shared__ float x[D];
    __shared__ float red[256];
    int t = blockIdx.x, ob = blockIdx.y, tid = threadIdx.x;
    for (int i = tid; i < D; i += 256) x[i] = ain[t * D + i];
    __syncthreads();
    int o = ob * 32 + (tid & 31), c = tid >> 5;
    const float* Wp = W + o;
    float acc = 0.f;
    int i0 = c * 128;
    for (int i = i0; i < i0 + 128; ++i) acc += x[i] * Wp[i * D];
    red[tid] = acc;
    __syncthreads();
    if (tid < 32) {
        float s = 0.f;
#pragma unroll
        for (int k = 0; k < 8; ++k) s += red[k * 32 + tid];
        h[t * D + ob * 32 + tid] += s;
    }
}

// u = gelu(rms(h,ln2) @ W1). grid (T, 128), block 256.
__global__ void k_ffn1(const float* __restrict__ h, const float* __restrict__ ln,
                       const float* __restrict__ W, float* __restrict__ u) {
    __shared__ float xn[D];
    __shared__ float red[256];
    int t = blockIdx.x, ob = blockIdx.y, tid = threadIdx.x;
    load_rms(h + t * D, ln, xn, red);
    int o = ob * 32 + (tid & 31), c = tid >> 5;
    const float* Wp = W + o;
    float acc = 0.f;
    int i0 = c * 128;
    for (int i = i0; i < i0 + 128; ++i) acc += xn[i] * Wp[(long)i * FF];
    red[tid] = acc;
    __syncthreads();
    if (tid < 32) {
        float s = 0.f;
#pragma unroll
        for (int k = 0; k < 8; ++k) s += red[k * 32 + tid];
        float y = s;
        float g3 = 0.5f * y * (1.f + tanhf(0.7978845608028654f * (y + 0.044715f * y * y * y)));
        u[t * FF + ob * 32 + tid] = g3;
    }
}

// h += u @ W2. grid (T, 64), block 256. 16 outputs x 16 chunks of 256.
__global__ void k_ffn2(const float* __restrict__ u, const float* __restrict__ W,
                       float* __restrict__ h) {
    __shared__ float x[FF];
    __shared__ float red[256];
    int t = blockIdx.x, ob = blockIdx.y, tid = threadIdx.x;
    for (int i = tid; i < FF; i += 256) x[i] = u[t * FF + i];
    __syncthreads();
    int o = ob * 16 + (tid & 15), c = tid >> 4;
    const float* Wp = W + o;
    float acc = 0.f;
    int i0 = c * 256;
    for (int i = i0; i < i0 + 256; ++i) acc += x[i] * Wp[i * D];
    red[tid] = acc;
    __syncthreads();
    if (tid < 16) {
        float s = 0.f;
#pragma unroll
        for (int k = 0; k < 16; ++k) s += red[k * 16 + tid];
        h[t * D + ob * 16 + tid] += s;
    }
}

// logits = heads[g] @ rms(h_last, ln_f). grid 64, block 256 (4 waves x 8 rows).
__global__ void k_head(const float* __restrict__ h, const float* __restrict__ lnf,
                       const float* __restrict__ Hd, float* __restrict__ logits) {
    __shared__ float xn[D];
    __shared__ float red[256];
    load_rms(h, lnf, xn, red);
    int tid = threadIdx.x, lane = tid & 63, w = tid >> 6;
    int rbase = blockIdx.x * 32 + w * 8;
    for (int r = 0; r < 8; ++r) {
        const float* row = Hd + (long)(rbase + r) * D;
        float acc = 0.f;
#pragma unroll
        for (int it = 0; it < 4; ++it) {
            int idx = it * 256 + lane * 4;
            float4 a = *(const float4*)(row + idx);
            acc += a.x * xn[idx] + a.y * xn[idx + 1] + a.z * xn[idx + 2] + a.w * xn[idx + 3];
        }
        acc = wave_reduce_sum(acc);
        if (lane == 0) logits[rbase + r] = acc;
    }
}

// top-50 -> sample -> code -> embed gather; updates out and next h. 1 block x 256.
__global__ void k_sample(const float* __restrict__ logits, const float* __restrict__ temp,
                         const float* __restrict__ unis, const float* __restrict__ embeds,
                         int g, float* __restrict__ h, float* __restrict__ out) {
    __shared__ float topv[TOPK];
    __shared__ int topi[TOPK];
    __shared__ int s_code;
    int tid = threadIdx.x;
    if (tid < 64) {
        int lane = tid;
        float v[32];
#pragma unroll
        for (int j = 0; j < 32; ++j) v[j] = logits[j * 64 + lane];
        for (int r = 0; r < TOPK; ++r) {
            float bv = v[0];
            int bj = 0;
#pragma unroll
            for (int j = 1; j < 32; ++j)
                if (v[j] > bv) { bv = v[j]; bj = j; }
            int bidx = bj * 64 + lane;
#pragma unroll
            for (int m = 32; m >= 1; m >>= 1) {
                float ov = __shfl_xor(bv, m, 64);
                int oi = __shfl_xor(bidx, m, 64);
                if (ov > bv || (ov == bv && oi < bidx)) { bv = ov; bidx = oi; }
            }
            if (lane == 0) { topv[r] = bv; topi[r] = bidx; }
            if ((bidx & 63) == lane) v[bidx >> 6] = -3.0e38f;
        }
    }
    __syncthreads();
    if (tid == 0) {
        float t = fmaxf(temp[0], 1e-5f);
        float m = topv[0] / t;
        float p[TOPK];
        float l = 0.f;
        for (int j = 0; j < TOPK; ++j) { p[j] = expf(topv[j] / t - m); l += p[j]; }
        float u = unis[g];
        u = fminf(fmaxf(u, 1e-6f), 1.f - 1e-6f);
        float cdf = 0.f;
        int choice = 0;
        bool found = false;
        for (int j = 0; j < TOPK; ++j) {
            cdf += p[j] / l;
            if (!found && cdf >= u) { choice = j; found = true; }
        }
        s_code = topi[choice];
        out[g] = (float)s_code;
    }
    __syncthreads();
    int code = s_code;
    const float* e = embeds + ((long)g * VOC + code) * D;
    for (int i = tid; i < D; i += 256) {
        float ev = e[i];
        out[NGRP + i] += ev;
        h[i] = ev;
    }
}

extern "C" void kernel_launch(void* const* d_in, const int* in_sizes, int n_in,
                              void* d_out, int out_size, void* d_ws, size_t ws_size,
                              hipStream_t stream) {
    const float* talker = (const float*)d_in[0];
    const float* code0  = (const float*)d_in[1];
    const float* temp   = (const float*)d_in[2];
    const float* unis   = (const float*)d_in[3];
    const float* heads  = (const float*)d_in[4];
    const float* embeds = (const float*)d_in[5];
    const float* ln1    = (const float*)d_in[6];
    const float* ln2    = (const float*)d_in[7];
    const float* lnf    = (const float*)d_in[8];
    const float* wq     = (const float*)d_in[9];
    const float* wk     = (const float*)d_in[10];
    const float* wv     = (const float*)d_in[11];
    const float* wo     = (const float*)d_in[12];
    const float* w1     = (const float*)d_in[13];
    const float* w2     = (const float*)d_in[14];
    float* out = (float*)d_out;

    float* ws   = (float*)d_ws;
    float* h    = ws;            // 2*1024
    float* qkvb = ws + 2048;     // 2*3*1024
    float* ao   = ws + 8192;     // 2*1024
    float* kc   = ws + 10240;    // 2*16*1024
    float* vc   = ws + 43008;    // 2*16*1024
    float* ub   = ws + 75776;    // 2*4096
    float* lg   = ws + 83968;    // 2048

    auto step = [&](int T, int basePos) {
        for (int l = 0; l < NL; ++l) {
            k_qkv<<<dim3(T, 3, 32), 256, 0, stream>>>(h, ln1 + l * D,
                wq + (long)l * D * D, wk + (long)l * D * D, wv + (long)l * D * D, qkvb);
            k_attn<<<dim3(T, NHEADS), 64, 0, stream>>>(qkvb, kc + (long)l * MAXS * D,
                vc + (long)l * MAXS * D, ao, basePos);
            k_wo<<<dim3(T, 32), 256, 0, stream>>>(ao, wo + (long)l * D * D, h);
            k_ffn1<<<dim3(T, 128), 256, 0, stream>>>(h, ln2 + l * D, w1 + (long)l * D * FF, ub);
            k_ffn2<<<dim3(T, 64), 256, 0, stream>>>(ub, w2 + (long)l * FF * D, h);
        }
    };

    k_init<<<4, 256, 0, stream>>>(talker, code0, h, out);
    step(2, 0);
    for (int g = 0; g < NGRP; ++g) {
        const float* hid = h + ((g == 0) ? 1 : 0) * D;
        k_head<<<64, 256, 0, stream>>>(hid, lnf, heads + (long)g * VOC * D, lg);
        k_sample<<<1, 256, 0, stream>>>(lg, temp, unis, embeds, g, h, out);
        if (g + 1 < NGRP) step(1, g + 2);
    }
}

// Round 2
// 2382.825 us; speedup vs baseline: 3.1733x; 3.1733x over previous
//
#include <hip/hip_runtime.h>
#include <math.h>

#define D      1024
#define NHEADS 16
#define HDIM   64
#define NL     2
#define FF     4096
#define NGRP   15
#define VOC    2048
#define TOPK   50
#define MAXS   16

__device__ __forceinline__ float wave_reduce_sum(float v) {
#pragma unroll
    for (int m = 32; m >= 1; m >>= 1) v += __shfl_xor(v, m, 64);
    return v;
}

__device__ __forceinline__ float geluf(float y) {
    return 0.5f * y * (1.f + tanhf(0.7978845608028654f * (y + 0.044715f * y * y * y)));
}

// 256-thread block helper: xn[] = rms(src)*w, red[] is 256-float scratch.
__device__ __forceinline__ void load_rms(const float* __restrict__ src,
                                         const float* __restrict__ w,
                                         float* xn, float* red) {
    int tid = threadIdx.x;
    float ss = 0.f;
    for (int i = tid; i < D; i += 256) { float v = src[i]; xn[i] = v; ss += v * v; }
    red[tid] = ss;
    __syncthreads();
    for (int s = 128; s > 0; s >>= 1) {
        if (tid < s) red[tid] += red[tid + s];
        __syncthreads();
    }
    float inv = rsqrtf(red[0] / (float)D + 1e-6f);
    for (int i = tid; i < D; i += 256) xn[i] = xn[i] * inv * w[i];
    __syncthreads();
}

__global__ void k_init(const float* __restrict__ th, const float* __restrict__ c0,
                       float* __restrict__ h, float* __restrict__ out,
                       float* __restrict__ qkv) {
    int i = blockIdx.x * 256 + threadIdx.x;   // grid 4 x 256 -> i < 1024
    h[i] = th[i];
    h[D + i] = c0[i];
    out[NGRP + i] = c0[i];
#pragma unroll
    for (int j = 0; j < 6; ++j) qkv[j * 1024 + i] = 0.f;  // zero 2*3*1024
}

// qkv matvec, fused rms(ln1). grid (12, 8, T), block 256.
// blockIdx.x: m = x>>2 (q/k/v), ob = x&3 (256 outputs). blockIdx.y: K-split (8).
// Wave w handles K rows [ (y*4+w)*32, +32 ), lane holds float4 of 4 outputs.
__global__ void k_qkv(const float* __restrict__ h, const float* __restrict__ ln,
                      const float* __restrict__ Wq, const float* __restrict__ Wk,
                      const float* __restrict__ Wv, float* __restrict__ qkv) {
    __shared__ float xn[D];
    __shared__ float red[256];
    __shared__ float4 part[4][64];
    int t = blockIdx.z;
    int m = blockIdx.x >> 2, ob = blockIdx.x & 3;
    load_rms(h + t * D, ln, xn, red);
    const float* W = (m == 0) ? Wq : (m == 1) ? Wk : Wv;
    int tid = threadIdx.x, w = tid >> 6, lane = tid & 63;
    int obase = ob * 256;
    int kbase = (blockIdx.y * 4 + w) * 32;
    const float* Wp = W + (long)kbase * D + obase + lane * 4;
    float4 acc = {0.f, 0.f, 0.f, 0.f};
#pragma unroll 4
    for (int i = 0; i < 32; ++i) {
        float xv = xn[kbase + i];
        float4 wv = *(const float4*)(Wp + (long)i * D);
        acc.x += xv * wv.x; acc.y += xv * wv.y; acc.z += xv * wv.z; acc.w += xv * wv.w;
    }
    part[w][lane] = acc;
    __syncthreads();
    const float* p = (const float*)part;
    float s = p[tid] + p[256 + tid] + p[512 + tid] + p[768 + tid];
    atomicAdd(&qkv[t * 3 * D + m * D + obase + tid], s);
}

// attention with fused rope + cache write. grid (T, NHEADS), block 64 (one wave).
// Also zeroes ub for the upcoming ffn1 atomics.
__global__ void k_attn(const float* __restrict__ qkv, float* __restrict__ kc,
                       float* __restrict__ vc, float* __restrict__ ao,
                       float* __restrict__ ub, int basePos) {
    int t = blockIdx.x, hd = blockIdx.y, d = threadIdx.x;
    {   // zero ub slice: T*FF total over T*16 blocks -> 256 floats each
        int fb = blockIdx.x * NHEADS + blockIdx.y;
#pragma unroll
        for (int j = 0; j < 4; ++j) ub[fb * 256 + j * 64 + d] = 0.f;
    }
    int pos = basePos + t;
    int i = d & 31;
    float inv = __expf(-(float)i * (9.210340371976184f / 32.0f)); // 10000^(-i/32)
    float ang = (float)pos * inv;
    float cs = cosf(ang), sn = sinf(ang);

    float q = qkv[t * 3 * D + hd * HDIM + d];
    float qp = __shfl_xor(q, 32, 64);
    float qr = (d < 32) ? (q * cs - qp * sn) : (q * cs + qp * sn);

    float k0 = qkv[t * 3 * D + D + hd * HDIM + d];
    float kp = __shfl_xor(k0, 32, 64);
    float kr = (d < 32) ? (k0 * cs - kp * sn) : (k0 * cs + kp * sn);

    float v0 = qkv[t * 3 * D + 2 * D + hd * HDIM + d];
    kc[pos * D + hd * HDIM + d] = kr;
    vc[pos * D + hd * HDIM + d] = v0;

    float sc[MAXS];
#pragma unroll
    for (int s = 0; s < MAXS; ++s) {
        if (s > pos) break;
        float kv;
        if (s < basePos) {
            kv = kc[s * D + hd * HDIM + d];
        } else if (s == pos) {
            kv = kr;
        } else {
            float kk = qkv[(s - basePos) * 3 * D + D + hd * HDIM + d];
            float kkp = __shfl_xor(kk, 32, 64);
            float a2 = (float)s * inv;
            float c2 = cosf(a2), s2 = sinf(a2);
            kv = (d < 32) ? (kk * c2 - kkp * s2) : (kk * c2 + kkp * s2);
        }
        float dt = wave_reduce_sum(qr * kv);
        sc[s] = dt * 0.125f;  // 1/sqrt(64)
    }
    float mx = -1e30f;
#pragma unroll
    for (int s = 0; s < MAXS; ++s) { if (s > pos) break; mx = fmaxf(mx, sc[s]); }
    float l = 0.f;
#pragma unroll
    for (int s = 0; s < MAXS; ++s) { if (s > pos) break; sc[s] = expf(sc[s] - mx); l += sc[s]; }
    float o = 0.f;
#pragma unroll
    for (int s = 0; s < MAXS; ++s) {
        if (s > pos) break;
        float vv = (s < basePos) ? vc[s * D + hd * HDIM + d]
                                 : qkv[(s - basePos) * 3 * D + 2 * D + hd * HDIM + d];
        o += sc[s] * vv;
    }
    ao[t * D + hd * HDIM + d] = o / l;
}

// h += attn_out @ Wo. grid (4, 16, T), block 256. Also zeroes qkv for next layer.
__global__ void k_wo(const float* __restrict__ ain, const float* __restrict__ W,
                     float* __restrict__ h, float* __restrict__ qkv) {
    __shared__ float xn[D];
    __shared__ float4 part[4][64];
    int t = blockIdx.z, tid = threadIdx.x;
    if (blockIdx.x == 0 && tid < 192)  // 16 y-blocks * 192 = 3072 per token
        qkv[t * 3 * D + blockIdx.y * 192 + tid] = 0.f;
    for (int i = tid; i < D; i += 256) xn[i] = ain[t * D + i];
    __syncthreads();
    int w = tid >> 6, lane = tid & 63;
    int obase = blockIdx.x * 256;
    int kbase = (blockIdx.y * 4 + w) * 16;
    const float* Wp = W + (long)kbase * D + obase + lane * 4;
    float4 acc = {0.f, 0.f, 0.f, 0.f};
#pragma unroll 4
    for (int i = 0; i < 16; ++i) {
        float xv = xn[kbase + i];
        float4 wv = *(const float4*)(Wp + (long)i * D);
        acc.x += xv * wv.x; acc.y += xv * wv.y; acc.z += xv * wv.z; acc.w += xv * wv.w;
    }
    part[w][lane] = acc;
    __syncthreads();
    const float* p = (const float*)part;
    float s = p[tid] + p[256 + tid] + p[512 + tid] + p[768 + tid];
    atomicAdd(&h[t * D + obase + tid], s);
}

// ub += rms(h,ln2) @ W1 (pre-activation). grid (16, 8, T), block 256.
__global__ void k_ffn1(const float* __restrict__ h, const float* __restrict__ ln,
                       const float* __restrict__ W, float* __restrict__ ub) {
    __shared__ float xn[D];
    __shared__ float red[256];
    __shared__ float4 part[4][64];
    int t = blockIdx.z, tid = threadIdx.x;
    load_rms(h + t * D, ln, xn, red);
    int w = tid >> 6, lane = tid & 63;
    int obase = blockIdx.x * 256;
    int kbase = (blockIdx.y * 4 + w) * 32;
    const float* Wp = W + (long)kbase * FF + obase + lane * 4;
    float4 acc = {0.f, 0.f, 0.f, 0.f};
#pragma unroll 4
    for (int i = 0; i < 32; ++i) {
        float xv = xn[kbase + i];
        float4 wv = *(const float4*)(Wp + (long)i * FF);
        acc.x += xv * wv.x; acc.y += xv * wv.y; acc.z += xv * wv.z; acc.w += xv * wv.w;
    }
    part[w][lane] = acc;
    __syncthreads();
    const float* p = (const float*)part;
    float s = p[tid] + p[256 + tid] + p[512 + tid] + p[768 + tid];
    atomicAdd(&ub[t * FF + obase + tid], s);
}

// h += gelu(ub) @ W2. grid (4, 32, T), block 256. Block covers K rows [y*128, +128).
__global__ void k_ffn2(const float* __restrict__ ub, const float* __restrict__ W,
                       float* __restrict__ h) {
    __shared__ float xs[128];
    __shared__ float4 part[4][64];
    int t = blockIdx.z, tid = threadIdx.x;
    int kblk = blockIdx.y * 128;
    if (tid < 128) xs[tid] = geluf(ub[t * FF + kblk + tid]);
    __syncthreads();
    int w = tid >> 6, lane = tid & 63;
    int obase = blockIdx.x * 256;
    int kloc = w * 32;
    const float* Wp = W + (long)(kblk + kloc) * D + obase + lane * 4;
    float4 acc = {0.f, 0.f, 0.f, 0.f};
#pragma unroll 4
    for (int i = 0; i < 32; ++i) {
        float xv = xs[kloc + i];
        float4 wv = *(const float4*)(Wp + (long)i * D);
        acc.x += xv * wv.x; acc.y += xv * wv.y; acc.z += xv * wv.z; acc.w += xv * wv.w;
    }
    part[w][lane] = acc;
    __syncthreads();
    const float* p = (const float*)part;
    float s = p[tid] + p[256 + tid] + p[512 + tid] + p[768 + tid];
    atomicAdd(&h[t * D + obase + tid], s);
}

// logits = heads[g] @ rms(h_last, ln_f). grid 128, block 256 (4 waves x 4 rows).
// Head rows are contiguous (V,D) -> per-wave full dot, no atomics needed.
__global__ void k_head(const float* __restrict__ h, const float* __restrict__ lnf,
                       const float* __restrict__ Hd, float* __restrict__ logits) {
    __shared__ float xn[D];
    __shared__ float red[256];
    load_rms(h, lnf, xn, red);
    int tid = threadIdx.x, lane = tid & 63, w = tid >> 6;
    int rbase = blockIdx.x * 16 + w * 4;
#pragma unroll
    for (int r = 0; r < 4; ++r) {
        const float* row = Hd + (long)(rbase + r) * D;
        float acc = 0.f;
#pragma unroll
        for (int it = 0; it < 4; ++it) {
            int idx = it * 256 + lane * 4;
            float4 a = *(const float4*)(row + idx);
            acc += a.x * xn[idx] + a.y * xn[idx + 1] + a.z * xn[idx + 2] + a.w * xn[idx + 3];
        }
        acc = wave_reduce_sum(acc);
        if (lane == 0) logits[rbase + r] = acc;
    }
}

// top-50 -> sample -> code -> embed gather; updates out and next h. 1 block x 256.
__global__ void k_sample(const float* __restrict__ logits, const float* __restrict__ temp,
                         const float* __restrict__ unis, const float* __restrict__ embeds,
                         int g, float* __restrict__ h, float* __restrict__ out) {
    __shared__ float topv[TOPK];
    __shared__ int topi[TOPK];
    __shared__ int s_code;
    int tid = threadIdx.x;
    if (tid < 64) {
        int lane = tid;
        float v[32];
#pragma unroll
        for (int j = 0; j < 32; ++j) v[j] = logits[j * 64 + lane];
        for (int r = 0; r < TOPK; ++r) {
            float bv = v[0];
            int bj = 0;
#pragma unroll
            for (int j = 1; j < 32; ++j)
                if (v[j] > bv) { bv = v[j]; bj = j; }
            int bidx = bj * 64 + lane;
#pragma unroll
            for (int m = 32; m >= 1; m >>= 1) {
                float ov = __shfl_xor(bv, m, 64);
                int oi = __shfl_xor(bidx, m, 64);
                if (ov > bv || (ov == bv && oi < bidx)) { bv = ov; bidx = oi; }
            }
            if (lane == 0) { topv[r] = bv; topi[r] = bidx; }
            if ((bidx & 63) == lane) v[bidx >> 6] = -3.0e38f;
        }
    }
    __syncthreads();
    if (tid == 0) {
        float t = fmaxf(temp[0], 1e-5f);
        float m = topv[0] / t;
        float p[TOPK];
        float l = 0.f;
        for (int j = 0; j < TOPK; ++j) { p[j] = expf(topv[j] / t - m); l += p[j]; }
        float u = unis[g];
        u = fminf(fmaxf(u, 1e-6f), 1.f - 1e-6f);
        float cdf = 0.f;
        int choice = 0;
        bool found = false;
        for (int j = 0; j < TOPK; ++j) {
            cdf += p[j] / l;
            if (!found && cdf >= u) { choice = j; found = true; }
        }
        s_code = topi[choice];
        out[g] = (float)s_code;
    }
    __syncthreads();
    int code = s_code;
    const float* e = embeds + ((long)g * VOC + code) * D;
    for (int i = tid; i < D; i += 256) {
        float ev = e[i];
        out[NGRP + i] += ev;
        h[i] = ev;
    }
}

extern "C" void kernel_launch(void* const* d_in, const int* in_sizes, int n_in,
                              void* d_out, int out_size, void* d_ws, size_t ws_size,
                              hipStream_t stream) {
    const float* talker = (const float*)d_in[0];
    const float* code0  = (const float*)d_in[1];
    const float* temp   = (const float*)d_in[2];
    const float* unis   = (const float*)d_in[3];
    const float* heads  = (const float*)d_in[4];
    const float* embeds = (const float*)d_in[5];
    const float* ln1    = (const float*)d_in[6];
    const float* ln2    = (const float*)d_in[7];
    const float* lnf    = (const float*)d_in[8];
    const float* wq     = (const float*)d_in[9];
    const float* wk     = (const float*)d_in[10];
    const float* wv     = (const float*)d_in[11];
    const float* wo     = (const float*)d_in[12];
    const float* w1     = (const float*)d_in[13];
    const float* w2     = (const float*)d_in[14];
    float* out = (float*)d_out;

    float* ws   = (float*)d_ws;
    float* h    = ws;            // 2*1024
    float* qkvb = ws + 2048;     // 2*3*1024
    float* ao   = ws + 8192;     // 2*1024
    float* kc   = ws + 10240;    // 2*16*1024
    float* vc   = ws + 43008;    // 2*16*1024
    float* ub   = ws + 75776;    // 2*4096
    float* lg   = ws + 83968;    // 2048

    auto step = [&](int T, int basePos) {
        for (int l = 0; l < NL; ++l) {
            k_qkv<<<dim3(12, 8, T), 256, 0, stream>>>(h, ln1 + l * D,
                wq + (long)l * D * D, wk + (long)l * D * D, wv + (long)l * D * D, qkvb);
            k_attn<<<dim3(T, NHEADS), 64, 0, stream>>>(qkvb, kc + (long)l * MAXS * D,
                vc + (long)l * MAXS * D, ao, ub, basePos);
            k_wo<<<dim3(4, 16, T), 256, 0, stream>>>(ao, wo + (long)l * D * D, h, qkvb);
            k_ffn1<<<dim3(16, 8, T), 256, 0, stream>>>(h, ln2 + l * D, w1 + (long)l * D * FF, ub);
            k_ffn2<<<dim3(4, 32, T), 256, 0, stream>>>(ub, w2 + (long)l * FF * D, h);
        }
    };

    k_init<<<4, 256, 0, stream>>>(talker, code0, h, out, qkvb);
    step(2, 0);
    for (int g = 0; g < NGRP; ++g) {
        const float* hid = h + ((g == 0) ? 1 : 0) * D;
        k_head<<<128, 256, 0, stream>>>(hid, lnf, heads + (long)g * VOC * D, lg);
        k_sample<<<1, 256, 0, stream>>>(lg, temp, unis, embeds, g, h, out);
        if (g + 1 < NGRP) step(1, g + 2);
    }
}